// Round 7
// baseline (284.287 us; speedup 1.0000x reference)
//
#include <hip/hip_runtime.h>

// ---------------------------------------------------------------------------
// MultiHeadAttention: x[4,2048,1024] fp32 -> QKV proj -> MHA (16 heads, d=64)
// -> out proj. bf16 MFMA everywhere (fp32 accum), flash attention.
// R7: attention load-issue scheduling — every L2 load >=400cyc from its use:
//   kf1 at iter top (S1 ~400cyc later), vf1 after S0 (PV1 ~600cyc later),
//   next-tile kfA after S0 / vfA after PV0 (consumed next iter ~full iter).
// Peak live kept ~96 VGPR (4 waves/SIMD canary: VGPR<=96, WRITE_SIZE~16MB).
// Converts merged into one launch.
// ---------------------------------------------------------------------------

typedef __bf16 bf16x8 __attribute__((ext_vector_type(8)));
typedef float f32x4 __attribute__((ext_vector_type(4)));
typedef float f32x16 __attribute__((ext_vector_type(16)));

#define DEV __device__ __forceinline__

DEV unsigned short f2b(float x) {          // fp32 -> bf16 RNE
  unsigned int u = __float_as_uint(x);
  u += 0x7fffu + ((u >> 16) & 1u);
  return (unsigned short)(u >> 16);
}

// pack two fp32 -> bf16 pair (round-half-up: 1 add each + 1 v_perm)
DEV unsigned int pk_bf16(float a, float b) {   // (bf16(b)<<16) | bf16(a)
  unsigned int ua = __float_as_uint(a) + 0x8000u;
  unsigned int ub = __float_as_uint(b) + 0x8000u;
  return __builtin_amdgcn_perm(ub, ua, 0x07060302u);  // bytes {b3,b2,a3,a2}
}

#if __has_builtin(__builtin_amdgcn_exp2f)
DEV float exp2_fast(float x) { return __builtin_amdgcn_exp2f(x); }
#else
DEV float exp2_fast(float x) { return exp2f(x); }
#endif

// async global->LDS, 16B per lane (unpadded lane-contiguous dest only).
DEV void g2l16(const void* g, void* l) {
  __builtin_amdgcn_global_load_lds(
      (const __attribute__((address_space(1))) unsigned int*)(unsigned long long)g,
      (__attribute__((address_space(3))) unsigned int*)(unsigned int)(unsigned long long)l,
      16, 0, 0);
}

// ---------------------------------------------------------------------------
// merged convert kernel. grid 12288 x 256:
//   bx < 8192          : x fp32 -> bf16 (4 elems/thread, float4)
//   bx >= 8192 (4096)  : weight transpose W[1024][N] fp32 -> Wt[N][1024] bf16
//                        t = bx-8192: nb = t>>5 (0..127), kb = t&31
//                        nb < 96 -> W_qkv (N=3072); else W_out (N=1024)
// ---------------------------------------------------------------------------
__global__ void cvt_all_kernel(const float* __restrict__ x,
                               unsigned short* __restrict__ xb,
                               const float* __restrict__ Wq,
                               unsigned short* __restrict__ Wqt,
                               const float* __restrict__ Wo,
                               unsigned short* __restrict__ Wot) {
  const int tid = threadIdx.x;
  int bx = blockIdx.x;
  if (bx < 8192) {
    int i = bx * 256 + tid;
    float4 v = ((const float4*)x)[i];
    ushort4 o;
    o.x = f2b(v.x); o.y = f2b(v.y); o.z = f2b(v.z); o.w = f2b(v.w);
    ((ushort4*)xb)[i] = o;
    return;
  }
  __shared__ float tile[32][33];
  int t = bx - 8192;
  int nb = t >> 5, kb = t & 31;
  const float* W;
  unsigned short* Wt;
  int N;
  if (nb < 96) { W = Wq; Wt = Wqt; N = 3072; }
  else         { W = Wo; Wt = Wot; N = 1024; nb -= 96; }
  int n0 = nb * 32, k0 = kb * 32;
  int tx = tid & 31, ty = tid >> 5;                // (32, 8)
#pragma unroll
  for (int i = 0; i < 32; i += 8)
    tile[ty + i][tx] = W[(size_t)(k0 + ty + i) * N + n0 + tx];
  __syncthreads();
#pragma unroll
  for (int i = 0; i < 32; i += 8)
    Wt[(size_t)(n0 + ty + i) * 1024 + k0 + tx] = f2b(tile[tx][ty + i]);
}

// ---------------------------------------------------------------------------
// GEMM  C[M,N] = A[M,1024] @ Bt[N,1024]^T + bias   (m97-style, 128x128, BK=32)
// MODE 0: N=3072. Epilogue:
//   cols 0..1023   -> Q (scaled 0.125*log2e) row-major qout[8192][1024]
//   cols 1024..2047-> K in 32x32 A-frag order:
//     kfr[head][kt][f=kt32*4+(d>>4)][lane'=(k64&31)+32*((d>>3)&1)][j=d&7]
//   cols 2048..3071-> V^T in 32x32 A-frag order:
//     vfr[head][kt][f=(d>>5)*4+kc][lane'=(d&31)+32*(k16hi)][j]
// MODE 1: N=1024, epilogue writes fp32 fout[8192][1024].
// ---------------------------------------------------------------------------
#define QSCALE 0.18033688011112042f   // 0.125 * log2(e): softmax in exp2 domain

template <int MODE>
__global__ __launch_bounds__(256, 2)
void gemm_bt_kernel(const unsigned short* __restrict__ A,
                    const unsigned short* __restrict__ Bt,
                    const float* __restrict__ bias,
                    unsigned short* __restrict__ qout,
                    unsigned short* __restrict__ kfrout,
                    unsigned short* __restrict__ vfrout,
                    float* __restrict__ fout) {
  constexpr int K = 1024;
  __shared__ unsigned short As[128 * 32];
  __shared__ unsigned short Bs[128 * 32];

  const int tid = threadIdx.x;
  const int lane = tid & 63;
  const int w = tid >> 6;
  const int wm = w & 1, wn = w >> 1;          // 2x2 wave grid, 64x64 per wave
  const int l15 = lane & 15, quad = lane >> 4;
  const int m0 = blockIdx.y * 128;
  const int n0 = blockIdx.x * 128;

  const unsigned short* Ag = A + (size_t)m0 * K;
  const unsigned short* Bg = Bt + (size_t)n0 * K;

  // chunk c (0..511): row=c/4, 16B part=c%4 ; LDS landing = c*16 bytes
  const int c0 = tid, c1 = tid + 256;
  const size_t ga0 = (size_t)(c0 >> 2) * K + (size_t)(c0 & 3) * 8;
  const size_t ga1 = (size_t)(c1 >> 2) * K + (size_t)(c1 & 3) * 8;
  unsigned short* la0 = &As[c0 * 8];
  unsigned short* la1 = &As[c1 * 8];
  unsigned short* lb0 = &Bs[c0 * 8];
  unsigned short* lb1 = &Bs[c1 * 8];

  f32x4 acc[4][4] = {};

  for (int kt = 0; kt < K; kt += 32) {
    g2l16(Ag + ga0 + kt, la0);
    g2l16(Ag + ga1 + kt, la1);
    g2l16(Bg + ga0 + kt, lb0);
    g2l16(Bg + ga1 + kt, lb1);
    __syncthreads();   // compiler emits vmcnt(0) drain before s_barrier
    bf16x8 af[4], bfr[4];
#pragma unroll
    for (int i = 0; i < 4; ++i) {
      af[i]  = *(const bf16x8*)&As[(wm * 64 + i * 16 + l15) * 32 + quad * 8];
      bfr[i] = *(const bf16x8*)&Bs[(wn * 64 + i * 16 + l15) * 32 + quad * 8];
    }
#pragma unroll
    for (int mi = 0; mi < 4; ++mi)
#pragma unroll
      for (int ni = 0; ni < 4; ++ni)
        acc[mi][ni] = __builtin_amdgcn_mfma_f32_16x16x32_bf16(
            af[mi], bfr[ni], acc[mi][ni], 0, 0, 0);
    __syncthreads();
  }

  float bv[4];
#pragma unroll
  for (int ni = 0; ni < 4; ++ni)
    bv[ni] = bias[n0 + wn * 64 + ni * 16 + l15];

  if (MODE == 0) {
    const int sel = n0 >> 10;                 // uniform per block (1024%128==0)
    const int bbat = m0 >> 11;                // batch index (uniform per block)
    const int ktb = ((m0 & 2047) >> 6) + wm;  // key-tile (uniform per wave)
    if (sel == 0) {                           // ---- Q ----
#pragma unroll
      for (int mi = 0; mi < 4; ++mi) {
        int rb = m0 + wm * 64 + mi * 16 + quad * 4;
#pragma unroll
        for (int ni = 0; ni < 4; ++ni) {
          int c = (n0 & 1023) + wn * 64 + ni * 16 + l15;   // h*64+d
#pragma unroll
          for (int r = 0; r < 4; ++r)
            qout[(size_t)(rb + r) * 1024 + c] =
                f2b((acc[mi][ni][r] + bv[ni]) * QSCALE);
        }
      }
    } else if (sel == 1) {                    // ---- K -> 32x32 A-frag order ----
#pragma unroll
      for (int ni = 0; ni < 4; ++ni) {
        int c = (n0 & 1023) + wn * 64 + ni * 16 + l15;
        int h = c >> 6, d = c & 63;
        int fkc = d >> 4;                     // d-chunk (k-dim of MFMA)
        int lhi = (d >> 3) & 1;               // lane' bit5
        int j = d & 7;
#pragma unroll
        for (int mi = 0; mi < 4; ++mi) {
          int kt32 = mi >> 1;                 // key 32-subtile
          int l31b = (mi & 1) * 16 + quad * 4;  // lane'&31, +r below
          size_t base =
              ((((size_t)(bbat * 16 + h) * 32 + ktb) * 8) + kt32 * 4 + fkc) * 512 +
              (size_t)(l31b + 32 * lhi) * 8 + j;
#pragma unroll
          for (int r = 0; r < 4; ++r)
            kfrout[base + r * 8] = f2b(acc[mi][ni][r] + bv[ni]);
        }
      }
    } else {                                  // ---- V -> 32x32 A-frag order ----
      const int lhi = quad >> 1;              // key bit3 group
      const int j0 = (quad & 1) * 4;          // j base, +r consecutive
#pragma unroll
      for (int ni = 0; ni < 4; ++ni) {
        int c = (n0 & 1023) + wn * 64 + ni * 16 + l15;
        int h = c >> 6, d = c & 63;
        int dt = d >> 5;
        int lp = (d & 31) + 32 * lhi;
#pragma unroll
        for (int mi = 0; mi < 4; ++mi) {      // kc = mi (key 16-chunk)
          size_t base =
              ((((size_t)(bbat * 16 + h) * 32 + ktb) * 8) + dt * 4 + mi) * 512 +
              (size_t)lp * 8 + j0;
          ushort4 pk;
          pk.x = f2b(acc[mi][ni][0] + bv[ni]);
          pk.y = f2b(acc[mi][ni][1] + bv[ni]);
          pk.z = f2b(acc[mi][ni][2] + bv[ni]);
          pk.w = f2b(acc[mi][ni][3] + bv[ni]);
          *(ushort4*)&vfrout[base] = pk;
        }
      }
    }
  } else {
#pragma unroll
    for (int mi = 0; mi < 4; ++mi) {
      int rb = m0 + wm * 64 + mi * 16 + quad * 4;
#pragma unroll
      for (int ni = 0; ni < 4; ++ni) {
        int c = n0 + wn * 64 + ni * 16 + l15;
#pragma unroll
        for (int r = 0; r < 4; ++r)
          fout[(size_t)(rb + r) * 1024 + c] = acc[mi][ni][r] + bv[ni];
      }
    }
  }
}

// ---------------------------------------------------------------------------
// Flash attention, 32x32x16 MFMA, 32 q/wave, 128 q/block, 4 blocks/CU.
// R7 issue schedule (load -> use distance):
//   kf1 @ iter top        -> S1      (~400 cyc)
//   kfA next-tile @ post-S0 -> next S0 (~full iter)
//   vf1 @ post-S0         -> PV1     (~600 cyc)
//   vfA next-tile @ post-PV0 -> next PV0 (~full iter)
// ---------------------------------------------------------------------------
__global__ __launch_bounds__(256, 4)
void attn_kernel(const unsigned short* __restrict__ qg,
                 const unsigned short* __restrict__ kfr,
                 const unsigned short* __restrict__ vfr,
                 unsigned short* __restrict__ oat) {
  __shared__ unsigned short pt[128 * 72];   // P^T [q 128][key 64] pad 72

  const int tid = threadIdx.x;
  const int lane = tid & 63;
  const int w = tid >> 6;
  const int l31 = lane & 31, half = lane >> 5;

  // XCD swizzle: grid (8,128); XCD = bx. head = bx*8+(by>>4): a head's 16
  // q-blocks share an XCD; 8 heads * 512KB K+V = 4MB = its L2.
  const int head = blockIdx.x * 8 + (blockIdx.y >> 4);
  const int q0 = (blockIdx.y & 15) * 128;
  const int b = head >> 4, h = head & 15;
  const size_t tokbase = (size_t)b * 2048;
  const int q = q0 + w * 32 + l31;

  // Q frags, B-layout [k=d][n=q]: n=lane&31, k=kc*16 + half*8 + j
  bf16x8 qf[4];
#pragma unroll
  for (int kc = 0; kc < 4; ++kc)
    qf[kc] = *(const bf16x8*)(qg + (tokbase + q) * 1024 + h * 64 +
                              kc * 16 + half * 8);

  f32x16 oacc0 = {};                        // O^T d-tile 0 (AGPR, MFMA-only)
  f32x16 oacc1 = {};                        // O^T d-tile 1
  float lsum = 0.f;

  const bf16x8* kp = (const bf16x8*)kfr + (size_t)head * 32 * 512;
  const bf16x8* vp = (const bf16x8*)vfr + (size_t)head * 32 * 512;
  const int qrow = (w * 32 + l31) * 72;     // pt row base (wave-private)

  // preload kt=0: kfA <- kt32=0 frags, vfA <- dt=0 frags
  bf16x8 kfA[4], vfA[4];
#pragma unroll
  for (int f = 0; f < 4; ++f) {
    kfA[f] = kp[f * 64 + lane];
    vfA[f] = vp[f * 64 + lane];
  }

  for (int kt = 0; kt < 32; ++kt) {
    const bf16x8* kbase = kp + kt * 512;
    const bf16x8* vbase = vp + kt * 512;

    // kf1 (keys 32..63 of this tile): consumed at S1, far below
    bf16x8 kf1[4];
#pragma unroll
    for (int f = 0; f < 4; ++f) kf1[f] = kbase[(4 + f) * 64 + lane];

    // S tile 0 (keys 0..31) from kfA
    f32x16 st = {};
#pragma unroll
    for (int kc = 0; kc < 4; ++kc)
      st = __builtin_amdgcn_mfma_f32_32x32x16_bf16(kfA[kc], qf[kc], st, 0, 0, 0);

    // kfA done for this iter: preload next tile's kt32=0 (consumed next S0)
    if (kt < 31) {
#pragma unroll
      for (int f = 0; f < 4; ++f) kfA[f] = kbase[512 + f * 64 + lane];
    }

    // vf1 (dt1): consumed at PV1, ~600cyc below
    bf16x8 vf1[4];
#pragma unroll
    for (int f = 0; f < 4; ++f) vf1[f] = vbase[(4 + f) * 64 + lane];

    // softmax tile0 -> pt cols [0,32): key = 8*rg + 4*half + (0..3)
#pragma unroll
    for (int rg = 0; rg < 4; ++rg) {
      float p0 = exp2_fast(st[rg * 4 + 0]);
      float p1 = exp2_fast(st[rg * 4 + 1]);
      float p2 = exp2_fast(st[rg * 4 + 2]);
      float p3 = exp2_fast(st[rg * 4 + 3]);
      lsum += (p0 + p1) + (p2 + p3);
      uint2 pw;
      pw.x = pk_bf16(p0, p1);
      pw.y = pk_bf16(p2, p3);
      *(uint2*)&pt[qrow + 8 * rg + 4 * half] = pw;
    }

    // S tile 1 (keys 32..63) from kf1
    f32x16 st1 = {};
#pragma unroll
    for (int kc = 0; kc < 4; ++kc)
      st1 = __builtin_amdgcn_mfma_f32_32x32x16_bf16(kf1[kc], qf[kc], st1, 0, 0, 0);

#pragma unroll
    for (int rg = 0; rg < 4; ++rg) {
      float p0 = exp2_fast(st1[rg * 4 + 0]);
      float p1 = exp2_fast(st1[rg * 4 + 1]);
      float p2 = exp2_fast(st1[rg * 4 + 2]);
      float p3 = exp2_fast(st1[rg * 4 + 3]);
      lsum += (p0 + p1) + (p2 + p3);
      uint2 pw;
      pw.x = pk_bf16(p0, p1);
      pw.y = pk_bf16(p2, p3);
      *(uint2*)&pt[qrow + 32 + 8 * rg + 4 * half] = pw;
    }

    // P^T B-frags [k=key][n=q]: k = kc*16 + half*8 + j (wave-private rows:
    // same-wave lgkm ordering, no barrier)
    bf16x8 pf[4];
#pragma unroll
    for (int kc = 0; kc < 4; ++kc)
      pf[kc] = *(const bf16x8*)&pt[qrow + kc * 16 + half * 8];

    // PV d-tile 0 (vfA = dt0)
#pragma unroll
    for (int kc = 0; kc < 4; ++kc)
      oacc0 = __builtin_amdgcn_mfma_f32_32x32x16_bf16(vfA[kc], pf[kc], oacc0, 0, 0, 0);

    // vfA done: preload next tile's dt0 (consumed next PV0, ~full iter away)
    if (kt < 31) {
#pragma unroll
      for (int f = 0; f < 4; ++f) vfA[f] = vbase[512 + f * 64 + lane];
    }

    // PV d-tile 1 (vf1 = dt1)
#pragma unroll
    for (int kc = 0; kc < 4; ++kc)
      oacc1 = __builtin_amdgcn_mfma_f32_32x32x16_bf16(vf1[kc], pf[kc], oacc1, 0, 0, 0);
  }

  // epilogue: lanes l and l^32 hold complementary key-halves of same q
  float s = lsum + __shfl_xor(lsum, 32, 64);
  float inv = __builtin_amdgcn_rcpf(s);
  const size_t obase = (tokbase + q) * 1024 + h * 64;
#pragma unroll
  for (int rg = 0; rg < 4; ++rg) {
    int d0 = 8 * rg + 4 * half;               // 4 consecutive d per reg-group
    uint2 pw;
    pw.x = pk_bf16(oacc0[rg * 4 + 0] * inv, oacc0[rg * 4 + 1] * inv);
    pw.y = pk_bf16(oacc0[rg * 4 + 2] * inv, oacc0[rg * 4 + 3] * inv);
    *(uint2*)&oat[obase + d0] = pw;
    pw.x = pk_bf16(oacc1[rg * 4 + 0] * inv, oacc1[rg * 4 + 1] * inv);
    pw.y = pk_bf16(oacc1[rg * 4 + 2] * inv, oacc1[rg * 4 + 3] * inv);
    *(uint2*)&oat[obase + 32 + d0] = pw;
  }
}

// ---------------------------------------------------------------------------
// launch
// ---------------------------------------------------------------------------
extern "C" void kernel_launch(void* const* d_in, const int* in_sizes, int n_in,
                              void* d_out, int out_size, void* d_ws, size_t ws_size,
                              hipStream_t stream) {
  const float* x    = (const float*)d_in[0];   // [4,2048,1024]
  const float* Wqkv = (const float*)d_in[1];   // [1024,3072]
  const float* bqkv = (const float*)d_in[2];   // [3072]
  const float* Wout = (const float*)d_in[3];   // [1024,1024]
  const float* bout = (const float*)d_in[4];   // [1024]
  float* out = (float*)d_out;                  // [4,2048,1024] fp32

  char* ws = (char*)d_ws;
  unsigned short* xb  = (unsigned short*)(ws + (size_t)0);          // 16 MiB
  unsigned short* wqt = (unsigned short*)(ws + ((size_t)16 << 20)); //  6 MiB
  unsigned short* wot = (unsigned short*)(ws + ((size_t)22 << 20)); //  2 MiB
  unsigned short* qbf = (unsigned short*)(ws + ((size_t)24 << 20)); // 16 MiB
  unsigned short* kfr = (unsigned short*)(ws + ((size_t)40 << 20)); // 16 MiB
  unsigned short* vfr = (unsigned short*)(ws + ((size_t)56 << 20)); // 16 MiB
  unsigned short* oat = (unsigned short*)(ws + ((size_t)72 << 20)); // 16 MiB

  cvt_all_kernel<<<12288, 256, 0, stream>>>(x, xb, Wqkv, wqt, Wout, wot);

  gemm_bt_kernel<0><<<dim3(24, 64), 256, 0, stream>>>(
      xb, wqt, bqkv, qbf, kfr, vfr, nullptr);

  attn_kernel<<<dim3(8, 128), 256, 0, stream>>>(qbf, kfr, vfr, oat);

  gemm_bt_kernel<1><<<dim3(8, 64), 256, 0, stream>>>(
      oat, wot, bout, nullptr, nullptr, nullptr, out);
}